// Round 6
// baseline (1825.266 us; speedup 1.0000x reference)
//
#include <hip/hip_runtime.h>
#include <hip/hip_bf16.h>
#include <math.h>

#define N_NODES 50000
#define E_EDGES 800000
#define ET (E_EDGES + N_NODES)
#define IN_DIM 3000
#define HID 512
#define LAT 30
#define XH_STRIDE 32
#define NEG_SLOPE 0.2f
#define KPAD 3072
#define ENC_NT 94   // ceil(3000/32)
#define DEC_NT 16   // 512/32
#define APITCH 40   // padded A-row pitch in bf16 elems (80B, 16B-aligned)

typedef __bf16 bfv8 __attribute__((ext_vector_type(8)));
typedef float f32x4 __attribute__((ext_vector_type(4)));

__device__ __forceinline__ float eluf(float x) { return x > 0.f ? x : expm1f(x); }

__device__ __forceinline__ unsigned fkey(float f) {
    unsigned u = __float_as_uint(f);
    return (u & 0x80000000u) ? ~u : (u | 0x80000000u);
}
__device__ __forceinline__ float funkey(unsigned k) {
    unsigned u = (k & 0x80000000u) ? (k ^ 0x80000000u) : ~k;
    return __uint_as_float(u);
}

__global__ void k_init(float* __restrict__ zbuf, unsigned* __restrict__ amax, float* __restrict__ denom) {
    int gid = blockIdx.x * 256 + threadIdx.x;
    if (gid < N_NODES * XH_STRIDE) zbuf[gid] = 0.f;
    if (gid < N_NODES) { amax[gid] = 0u; denom[gid] = 0.f; }
}

__global__ void k_transpose_w(const float* __restrict__ w, float* __restrict__ wt) {
    int idx = blockIdx.x * 256 + threadIdx.x;
    if (idx < HID * LAT) {
        int j = idx / LAT, c = idx % LAT;
        wt[c * HID + j] = w[idx];
    }
}

// enc_w1 [512][3000] f32 -> w1b [512][3072] bf16 (K-padded) and w1bt [3072][512] bf16 (transposed)
__global__ void k_conv_w(const float* __restrict__ w, __bf16* __restrict__ w1b, __bf16* __restrict__ w1bt) {
    int idx = blockIdx.x * 256 + threadIdx.x;
    if (idx >= HID * KPAD) return;
    int j = idx / KPAD, k = idx - j * KPAD;
    float v = (k < IN_DIM) ? w[(size_t)j * IN_DIM + k] : 0.f;
    __bf16 b = (__bf16)v;
    w1b[(size_t)j * KPAD + k] = b;
    w1bt[(size_t)k * HID + j] = b;
}

// ============ Encoder GEMM: h = elu(x @ enc_w1^T + b), M=50000 N=512 K=3000 ============
// 128x128 tile, BK=32. XCD swizzle: 4 col-blocks of a panel share one XCD (A L2 reuse).
// Bs: 3-buffer gll pipeline, counted vmcnt(2); XOR slot swizzle vs bank conflicts.
__global__ __launch_bounds__(256)
void k_enc_gemm(const float* __restrict__ A, const __bf16* __restrict__ Bb,
                const float* __restrict__ bias, float* __restrict__ C) {
    __shared__ __bf16 As[2][128 * APITCH];
    __shared__ __bf16 Bs[3][4096];
    const int tid = threadIdx.x;
    const int lane = tid & 63, wv = tid >> 6;
    const int wr = wv >> 1, wc = wv & 1;
    const int l16 = lane & 15, lh = lane >> 4;
    // grid (8,196): p = (y>>2)*8 + x  -> all 4 col-blocks of panel p on XCD (p%8)
    const int p = ((int)blockIdx.y >> 2) * 8 + (int)blockIdx.x;
    if (p > 390) return;
    const int i0 = p * 128;
    const int c0 = ((int)blockIdx.y & 3) * 128;

    const int arow = tid >> 2, akc = tid & 3;
    const int r0 = i0 + arow, r1 = i0 + arow + 64;
    const float* apA = A + (size_t)(r0 < N_NODES ? r0 : N_NODES - 1) * IN_DIM + akc * 8;
    const float* apB = A + (size_t)(r1 < N_NODES ? r1 : N_NODES - 1) * IN_DIM + akc * 8;

    f32x4 acc[4][4] = {};
    float4 a00, a01, a10, a11;

    auto stageB = [&](int kt, int b) {
#pragma unroll
        for (int s = 0; s < 2; ++s) {
            int g = wv * 2 + s;                    // [ks][half] chunk, lane -> slot lane
            int ks = g >> 1;
            int col = (g & 1) * 64 + (lane ^ (ks << 1));   // inverse slot swizzle on source
            const __bf16* src = Bb + (size_t)(c0 + col) * KPAD + kt + ks * 8;
            __builtin_amdgcn_global_load_lds(
                (const __attribute__((address_space(1))) void*)src,
                (__attribute__((address_space(3))) void*)(&Bs[b][(size_t)g * 512]),
                16, 0, 0);
        }
    };
    auto loadA = [&](int kt) {
        a00 = a01 = a10 = a11 = make_float4(0.f, 0.f, 0.f, 0.f);
        if (kt + akc * 8 < IN_DIM) {
            const float4* p0 = (const float4*)(apA + kt);
            a00 = p0[0]; a01 = p0[1];
            const float4* p1 = (const float4*)(apB + kt);
            a10 = p1[0]; a11 = p1[1];
        }
    };
    auto writeA = [&](int b) {
        bfv8 pk;
        pk[0] = (__bf16)a00.x; pk[1] = (__bf16)a00.y; pk[2] = (__bf16)a00.z; pk[3] = (__bf16)a00.w;
        pk[4] = (__bf16)a01.x; pk[5] = (__bf16)a01.y; pk[6] = (__bf16)a01.z; pk[7] = (__bf16)a01.w;
        *(bfv8*)&As[b][(size_t)arow * APITCH + akc * 8] = pk;
        pk[0] = (__bf16)a10.x; pk[1] = (__bf16)a10.y; pk[2] = (__bf16)a10.z; pk[3] = (__bf16)a10.w;
        pk[4] = (__bf16)a11.x; pk[5] = (__bf16)a11.y; pk[6] = (__bf16)a11.z; pk[7] = (__bf16)a11.w;
        *(bfv8*)&As[b][(size_t)(arow + 64) * APITCH + akc * 8] = pk;
    };

    // prologue: B tiles 0,1 staged; A tile 0 written; full drain
    stageB(0, 0);
    stageB(32, 1);
    loadA(0);
    writeA(0);
    asm volatile("s_waitcnt vmcnt(0) lgkmcnt(0)" ::: "memory");
    __builtin_amdgcn_s_barrier();
    __builtin_amdgcn_sched_barrier(0);

    int acur = 0;
    for (int t = 0; t < ENC_NT; ++t) {
        const int bt = t % 3;
        const bool nxt1 = (t + 1) < ENC_NT, nxt2 = (t + 2) < ENC_NT;
        if (nxt1) loadA((t + 1) * 32);                  // loads issued BEFORE glls
        if (nxt2) stageB((t + 2) * 32, (t + 2) % 3);    // stays in flight across barrier

        bfv8 af[4], bfr[4];
#pragma unroll
        for (int mi = 0; mi < 4; ++mi)
            af[mi] = *(const bfv8*)&As[acur][(size_t)(wr * 64 + mi * 16 + l16) * APITCH + lh * 8];
#pragma unroll
        for (int ni = 0; ni < 4; ++ni)
            bfr[ni] = *(const bfv8*)&Bs[bt][((size_t)lh * 128 + wc * 64 + ((ni * 16 + l16) ^ (lh << 1))) * 8];
#pragma unroll
        for (int mi = 0; mi < 4; ++mi)
#pragma unroll
            for (int ni = 0; ni < 4; ++ni)
                acc[mi][ni] = __builtin_amdgcn_mfma_f32_16x16x32_bf16(af[mi], bfr[ni], acc[mi][ni], 0, 0, 0);
        if (nxt1) writeA(acur ^ 1);
        if (nxt2) {
            // retires everything except the 2 newest glls (tile t+2); tile t+1's glls are older -> done
            asm volatile("s_waitcnt vmcnt(2) lgkmcnt(0)" ::: "memory");
        } else {
            asm volatile("s_waitcnt vmcnt(0) lgkmcnt(0)" ::: "memory");
        }
        __builtin_amdgcn_s_barrier();
        __builtin_amdgcn_sched_barrier(0);
        acur ^= 1;
    }

    // C/D layout: col = lane&15, row = (lane>>4)*4 + reg
#pragma unroll
    for (int ni = 0; ni < 4; ++ni) {
        int col = c0 + wc * 64 + ni * 16 + l16;
        float bv = bias[col];
#pragma unroll
        for (int mi = 0; mi < 4; ++mi) {
            int row0 = i0 + wr * 64 + mi * 16 + lh * 4;
#pragma unroll
            for (int r = 0; r < 4; ++r) {
                int row = row0 + r;
                if (row < N_NODES)
                    C[(size_t)row * HID + col] = eluf(acc[mi][ni][r] + bv);
            }
        }
    }
}

// ============ Decoder GEMM: x_recon = hd @ enc_w1 + dec_b2, M=50000 N=3000 K=512 ============
// Both operands gll-staged, 3-buffer counted-vmcnt(4) pipeline, XOR slot swizzle, XCD swizzle.
__global__ __launch_bounds__(256)
void k_dec_gemm(const __bf16* __restrict__ Ab, const __bf16* __restrict__ Bt,
                const float* __restrict__ bias, float* __restrict__ C) {
    __shared__ __bf16 As[3][4096];
    __shared__ __bf16 Bs[3][4096];
    const int tid = threadIdx.x;
    const int lane = tid & 63, wv = tid >> 6;
    const int wr = wv >> 1, wc = wv & 1;
    const int l16 = lane & 15, lh = lane >> 4;
    // grid (8,1176): p = (y/24)*8 + x, c = y%24 -> all 24 col-blocks of panel p on XCD (p%8)
    const int p = ((int)blockIdx.y / 24) * 8 + (int)blockIdx.x;
    if (p > 390) return;
    const int i0 = p * 128;
    const int c0 = ((int)blockIdx.y % 24) * 128;

    f32x4 acc[4][4] = {};

    auto stage = [&](int kt, int b) {
#pragma unroll
        for (int s = 0; s < 2; ++s) {
            int g = wv * 2 + s;
            int ks = g >> 1;
            int rc = (g & 1) * 64 + (lane ^ (ks << 1));    // inverse slot swizzle on source
            int row = i0 + rc; if (row >= N_NODES) row = N_NODES - 1;
            const __bf16* srcA = Ab + (size_t)row * HID + kt + ks * 8;
            __builtin_amdgcn_global_load_lds(
                (const __attribute__((address_space(1))) void*)srcA,
                (__attribute__((address_space(3))) void*)(&As[b][(size_t)g * 512]),
                16, 0, 0);
            const __bf16* srcB = Bt + (size_t)(c0 + rc) * HID + kt + ks * 8;
            __builtin_amdgcn_global_load_lds(
                (const __attribute__((address_space(1))) void*)srcB,
                (__attribute__((address_space(3))) void*)(&Bs[b][(size_t)g * 512]),
                16, 0, 0);
        }
    };

    stage(0, 0);
    stage(32, 1);
    asm volatile("s_waitcnt vmcnt(4) lgkmcnt(0)" ::: "memory");   // tile 0 done, tile 1 in flight
    __builtin_amdgcn_s_barrier();
    __builtin_amdgcn_sched_barrier(0);

#pragma unroll 1
    for (int t = 0; t < DEC_NT; ++t) {
        const int bt = t % 3;
        if (t + 2 < DEC_NT) stage((t + 2) * 32, (t + 2) % 3);
        bfv8 af[4], bfr[4];
#pragma unroll
        for (int mi = 0; mi < 4; ++mi)
            af[mi] = *(const bfv8*)&As[bt][((size_t)lh * 128 + wr * 64 + ((mi * 16 + l16) ^ (lh << 1))) * 8];
#pragma unroll
        for (int ni = 0; ni < 4; ++ni)
            bfr[ni] = *(const bfv8*)&Bs[bt][((size_t)lh * 128 + wc * 64 + ((ni * 16 + l16) ^ (lh << 1))) * 8];
#pragma unroll
        for (int mi = 0; mi < 4; ++mi)
#pragma unroll
            for (int ni = 0; ni < 4; ++ni)
                acc[mi][ni] = __builtin_amdgcn_mfma_f32_16x16x32_bf16(af[mi], bfr[ni], acc[mi][ni], 0, 0, 0);
        if (t + 2 < DEC_NT) {
            asm volatile("s_waitcnt vmcnt(4) lgkmcnt(0)" ::: "memory");  // retire tile t+1, keep t+2 flying
        } else {
            asm volatile("s_waitcnt vmcnt(0) lgkmcnt(0)" ::: "memory");
        }
        __builtin_amdgcn_s_barrier();
        __builtin_amdgcn_sched_barrier(0);
    }

#pragma unroll
    for (int ni = 0; ni < 4; ++ni) {
        int col = c0 + wc * 64 + ni * 16 + l16;
        if (col >= IN_DIM) continue;
        float bv = bias[col];
#pragma unroll
        for (int mi = 0; mi < 4; ++mi) {
            int row0 = i0 + wr * 64 + mi * 16 + lh * 4;
#pragma unroll
            for (int r = 0; r < 4; ++r) {
                int row = row0 + r;
                if (row < N_NODES)
                    C[(size_t)row * IN_DIM + col] = acc[mi][ni][r] + bv;
            }
        }
    }
}

// xh = h @ gat_w ; si/sj = att dots. 128 nodes per block.
__global__ __launch_bounds__(256)
void k_gat_proj(const float* __restrict__ h, const float* __restrict__ gat_w,
                const float* __restrict__ gat_att,
                float* __restrict__ xh, float* __restrict__ si, float* __restrict__ sj) {
    __shared__ float gwl[HID * LAT];
    __shared__ float atl[2 * LAT];
    int tid = threadIdx.x;
    for (int i = tid; i < HID * LAT; i += 256) gwl[i] = gat_w[i];
    if (tid < 2 * LAT) atl[tid] = gat_att[tid];
    __syncthreads();
    int c = tid & 31;
    bool act = c < LAT;
    for (int it = 0; it < 16; ++it) {
        int n = blockIdx.x * 128 + it * 8 + (tid >> 5);
        if (n >= N_NODES) continue;
        float accv = 0.f;
        const float4* h4 = (const float4*)(h + (size_t)n * HID);
#pragma unroll 4
        for (int j4 = 0; j4 < HID / 4; ++j4) {
            float4 hv = h4[j4];
            if (act) {
                int b = j4 * 4 * LAT + c;
                accv = fmaf(hv.x, gwl[b], accv);
                accv = fmaf(hv.y, gwl[b + LAT], accv);
                accv = fmaf(hv.z, gwl[b + 2 * LAT], accv);
                accv = fmaf(hv.w, gwl[b + 3 * LAT], accv);
            }
        }
        float xhv = act ? accv : 0.f;
        xh[(size_t)n * XH_STRIDE + c] = xhv;
        float sip = act ? atl[c] * xhv : 0.f;
        float sjp = act ? atl[LAT + c] * xhv : 0.f;
#pragma unroll
        for (int off = 16; off > 0; off >>= 1) {
            sip += __shfl_down(sip, off, 32);
            sjp += __shfl_down(sjp, off, 32);
        }
        if (c == 0) { si[n] = sip; sj[n] = sjp; }
    }
}

__global__ void k_edge_alpha(const int* __restrict__ ei, const float* __restrict__ eattr,
                             const float* __restrict__ si, const float* __restrict__ sj,
                             float* __restrict__ alphaE, unsigned* __restrict__ amax) {
    int e = blockIdx.x * 256 + threadIdx.x;
    if (e >= ET) return;
    int s, d; float w;
    if (e < E_EDGES) { s = ei[e]; d = ei[E_EDGES + e]; w = eattr[e]; }
    else { s = d = e - E_EDGES; w = 1.f; }
    float a = si[d] + sj[s];
    a = a >= 0.f ? a : NEG_SLOPE * a;
    a *= w;
    alphaE[e] = a;
    atomicMax(&amax[d], fkey(a));
}

// one thread per edge: v = exp(a - amax[d]); alphaE[e] = v; denom[d] += v
__global__ void k_edge_exp(const int* __restrict__ ei, float* __restrict__ alphaE,
                           const unsigned* __restrict__ amax, float* __restrict__ denom) {
    int e = blockIdx.x * 256 + threadIdx.x;
    if (e >= ET) return;
    int d = (e < E_EDGES) ? ei[E_EDGES + e] : (e - E_EDGES);
    float v = expf(alphaE[e] - funkey(amax[d]));
    alphaE[e] = v;
    atomicAdd(&denom[d], v);
}

// 32 lanes per edge: zbuf[d,:] += v * xh[s,:]
__global__ void k_edge_scatter(const int* __restrict__ ei, const float* __restrict__ alphaE,
                               const float* __restrict__ xh, float* __restrict__ zbuf) {
    int gid = blockIdx.x * 256 + threadIdx.x;
    int e = gid >> 5, c = gid & 31;
    if (e >= ET || c >= LAT) return;
    int s, d;
    if (e < E_EDGES) { s = ei[e]; d = ei[E_EDGES + e]; }
    else { s = d = e - E_EDGES; }
    atomicAdd(&zbuf[(size_t)d * XH_STRIDE + c], alphaE[e] * xh[(size_t)s * XH_STRIDE + c]);
}

// z = elu(zbuf/denom + gat_b); also writes zout
__global__ void k_z(const float* __restrict__ gat_b, const float* __restrict__ denom,
                    float* __restrict__ zbuf, float* __restrict__ zout) {
    int gid = blockIdx.x * 256 + threadIdx.x;
    int n = gid >> 5, c = gid & 31;
    if (n >= N_NODES) return;
    if (c < LAT) {
        float v = eluf(zbuf[gid] / (denom[n] + 1e-16f) + gat_b[c]);
        zbuf[gid] = v;
        zout[(size_t)n * LAT + c] = v;
    }
}

// hd[i,j] = elu( sum_c z[i,c]*dec_w1[j,c] + dec_b1[j] ) -> bf16
__global__ __launch_bounds__(256)
void k_dec1(const float* __restrict__ zbuf, const float* __restrict__ wt,
            const float* __restrict__ b, __bf16* __restrict__ hdb) {
    int gid = blockIdx.x * 256 + threadIdx.x;
    if (gid >= N_NODES * HID) return;
    int j = gid & (HID - 1);
    size_t i = (size_t)(gid >> 9);
    float acc = b[j];
#pragma unroll
    for (int c = 0; c < LAT; ++c)
        acc = fmaf(zbuf[i * XH_STRIDE + c], wt[c * HID + j], acc);
    hdb[gid] = (__bf16)eluf(acc);
}

extern "C" void kernel_launch(void* const* d_in, const int* in_sizes, int n_in,
                              void* d_out, int out_size, void* d_ws, size_t ws_size,
                              hipStream_t stream) {
    const float* x      = (const float*)d_in[0];
    const int*   ei     = (const int*)d_in[1];
    const float* eattr  = (const float*)d_in[2];
    const float* enc_w1 = (const float*)d_in[3];
    const float* enc_b1 = (const float*)d_in[4];
    const float* gat_w  = (const float*)d_in[5];
    const float* gat_att= (const float*)d_in[6];
    const float* gat_b  = (const float*)d_in[7];
    const float* dec_w1 = (const float*)d_in[8];
    const float* dec_b1 = (const float*)d_in[9];
    const float* dec_b2 = (const float*)d_in[10];

    float* out  = (float*)d_out;
    float* xrec = out;
    float* zout = out + (size_t)N_NODES * IN_DIM;

    float* ws = (float*)d_ws;
    float*    h      = ws;                         // 25,600,000 f32 (h; later hdb bf16 aliases front)
    float*    xh     = ws + 25600000;              //  1,600,000
    float*    zbuf   = ws + 27200000;              //  1,600,000
    float*    si     = ws + 28800000;
    float*    sj     = ws + 28850000;
    unsigned* amax   = (unsigned*)(ws + 28900000);
    float*    denom  = ws + 28950000;
    float*    alphaE = ws + 29000000;
    float*    wt     = ws + 29850000;
    __bf16*   w1b    = (__bf16*)(ws + 29865360);   // 512*3072 bf16
    __bf16*   w1bt   = (__bf16*)(ws + 30651792);   // 3072*512 bf16
    __bf16*   hdb    = (__bf16*)h;                 // 50000*512 bf16, aliases h (h dead by then)

    (void)in_sizes; (void)n_in; (void)out_size; (void)ws_size;

    k_init<<<(N_NODES * XH_STRIDE + 255) / 256, 256, 0, stream>>>(zbuf, amax, denom);
    k_transpose_w<<<(HID * LAT + 255) / 256, 256, 0, stream>>>(dec_w1, wt);
    k_conv_w<<<(HID * KPAD + 255) / 256, 256, 0, stream>>>(enc_w1, w1b, w1bt);

    {
        dim3 g(8, 196);   // XCD-swizzled: p=(y>>2)*8+x, c=y&3
        k_enc_gemm<<<g, 256, 0, stream>>>(x, w1b, enc_b1, h);
    }

    k_gat_proj<<<(N_NODES + 127) / 128, 256, 0, stream>>>(h, gat_w, gat_att, xh, si, sj);
    k_edge_alpha<<<(ET + 255) / 256, 256, 0, stream>>>(ei, eattr, si, sj, alphaE, amax);
    k_edge_exp<<<(ET + 255) / 256, 256, 0, stream>>>(ei, alphaE, amax, denom);
    k_edge_scatter<<<((size_t)ET * 32 + 255) / 256, 256, 0, stream>>>(ei, alphaE, xh, zbuf);
    k_z<<<(N_NODES * 32 + 255) / 256, 256, 0, stream>>>(gat_b, denom, zbuf, zout);
    k_dec1<<<(N_NODES * HID + 255) / 256, 256, 0, stream>>>(zbuf, wt, dec_b1, hdb);

    {
        dim3 g(8, 1176);  // XCD-swizzled: p=(y/24)*8+x, c=y%24
        k_dec_gemm<<<g, 256, 0, stream>>>(hdb, w1bt, dec_b2, xrec);
    }
}

// Round 7
// 1770.668 us; speedup vs baseline: 1.0308x; 1.0308x over previous
//
#include <hip/hip_runtime.h>
#include <hip/hip_bf16.h>
#include <math.h>

#define N_NODES 50000
#define E_EDGES 800000
#define ET (E_EDGES + N_NODES)
#define IN_DIM 3000
#define HID 512
#define LAT 30
#define XH_STRIDE 32
#define NEG_SLOPE 0.2f
#define KPAD 3072
#define ENC_NT 94    // ceil(3000/32)
#define DEC_NT 16    // 512/32
#define APLANE 1040  // bf16 elems per k-plane: 128 rows * 8 + 16 pad (2080B -> bank shift 8)

typedef __bf16 bfv8 __attribute__((ext_vector_type(8)));
typedef float f32x4 __attribute__((ext_vector_type(4)));

__device__ __forceinline__ float eluf(float x) { return x > 0.f ? x : expm1f(x); }

__global__ void k_init(unsigned* __restrict__ hist) {
    int gid = blockIdx.x * 256 + threadIdx.x;
    if (gid < N_NODES) hist[gid] = 0u;
}

__global__ void k_transpose_w(const float* __restrict__ w, float* __restrict__ wt) {
    int idx = blockIdx.x * 256 + threadIdx.x;
    if (idx < HID * LAT) {
        int j = idx / LAT, c = idx % LAT;
        wt[c * HID + j] = w[idx];
    }
}

// enc_w1 [512][3000] f32 -> w1b [512][3072] bf16 (K-padded) and w1bt [3072][512] bf16 (transposed)
__global__ void k_conv_w(const float* __restrict__ w, __bf16* __restrict__ w1b, __bf16* __restrict__ w1bt) {
    int idx = blockIdx.x * 256 + threadIdx.x;
    if (idx >= HID * KPAD) return;
    int j = idx / KPAD, k = idx - j * KPAD;
    float v = (k < IN_DIM) ? w[(size_t)j * IN_DIM + k] : 0.f;
    __bf16 b = (__bf16)v;
    w1b[(size_t)j * KPAD + k] = b;
    w1bt[(size_t)k * HID + j] = b;
}

// ============ Encoder GEMM: h = elu(x @ enc_w1^T + b), M=50000 N=512 K=3000 ============
// 128x128 tile, BK=32. XCD swizzle. 2-deep A register prefetch + 3-buffer B gll pipeline,
// counted vmcnt(6) so tile t+2's loads stay in flight across the barrier.
__global__ __launch_bounds__(256)
void k_enc_gemm(const float* __restrict__ A, const __bf16* __restrict__ Bb,
                const float* __restrict__ bias, float* __restrict__ C) {
    __shared__ __bf16 As[2][4 * APLANE];   // [buf][akc*APLANE + row*8]
    __shared__ __bf16 Bs[3][4096];         // [buf][(ks*2+half)*512 + col*8]
    const int tid = threadIdx.x;
    const int lane = tid & 63, wv = tid >> 6;
    const int wr = wv >> 1, wc = wv & 1;
    const int l16 = lane & 15, lh = lane >> 4;
    // grid (8,196): p = (y>>2)*8 + x  -> 4 col-blocks of panel p on one XCD
    const int p = ((int)blockIdx.y >> 2) * 8 + (int)blockIdx.x;
    if (p > 390) return;
    const int i0 = p * 128;
    const int c0 = ((int)blockIdx.y & 3) * 128;

    const int arow = tid >> 2, akc = tid & 3;
    const int r0 = i0 + arow, r1 = i0 + arow + 64;
    const float* apA = A + (size_t)(r0 < N_NODES ? r0 : N_NODES - 1) * IN_DIM + akc * 8;
    const float* apB = A + (size_t)(r1 < N_NODES ? r1 : N_NODES - 1) * IN_DIM + akc * 8;

    f32x4 acc[4][4] = {};
    float4 R0[4], R1[4];   // two A register sets (constant-indexed only)

    auto stageB = [&](int kt, int b) {
#pragma unroll
        for (int s = 0; s < 2; ++s) {
            int g = wv * 2 + s;                     // 0..7 = ks*2+half
            int col = (g & 1) * 64 + lane;
            int ks = g >> 1;
            const __bf16* src = Bb + (size_t)(c0 + col) * KPAD + kt + ks * 8;
            __builtin_amdgcn_global_load_lds(
                (const __attribute__((address_space(1))) void*)src,
                (__attribute__((address_space(3))) void*)(&Bs[b][(size_t)g * 512]),
                16, 0, 0);
        }
    };
    auto loadA = [&](int kt, float4* R) {
        R[0] = R[1] = R[2] = R[3] = make_float4(0.f, 0.f, 0.f, 0.f);
        if (kt + akc * 8 < IN_DIM) {
            const float4* p0 = (const float4*)(apA + kt);
            R[0] = p0[0]; R[1] = p0[1];
            const float4* p1 = (const float4*)(apB + kt);
            R[2] = p1[0]; R[3] = p1[1];
        }
    };
    auto writeA = [&](const float4* R, int b) {
        bfv8 pk;
        pk[0] = (__bf16)R[0].x; pk[1] = (__bf16)R[0].y; pk[2] = (__bf16)R[0].z; pk[3] = (__bf16)R[0].w;
        pk[4] = (__bf16)R[1].x; pk[5] = (__bf16)R[1].y; pk[6] = (__bf16)R[1].z; pk[7] = (__bf16)R[1].w;
        *(bfv8*)&As[b][(size_t)akc * APLANE + arow * 8] = pk;
        pk[0] = (__bf16)R[2].x; pk[1] = (__bf16)R[2].y; pk[2] = (__bf16)R[2].z; pk[3] = (__bf16)R[2].w;
        pk[4] = (__bf16)R[3].x; pk[5] = (__bf16)R[3].y; pk[6] = (__bf16)R[3].z; pk[7] = (__bf16)R[3].w;
        *(bfv8*)&As[b][(size_t)akc * APLANE + (arow + 64) * 8] = pk;
    };
    auto mfmaStep = [&](int tb, int bb) {
        bfv8 af[4], bfr[4];
#pragma unroll
        for (int mi = 0; mi < 4; ++mi)
            af[mi] = *(const bfv8*)&As[tb][(size_t)lh * APLANE + (wr * 64 + mi * 16 + l16) * 8];
#pragma unroll
        for (int ni = 0; ni < 4; ++ni)
            bfr[ni] = *(const bfv8*)&Bs[bb][((size_t)lh * 128 + wc * 64 + ni * 16 + l16) * 8];
#pragma unroll
        for (int mi = 0; mi < 4; ++mi)
#pragma unroll
            for (int ni = 0; ni < 4; ++ni)
                acc[mi][ni] = __builtin_amdgcn_mfma_f32_16x16x32_bf16(af[mi], bfr[ni], acc[mi][ni], 0, 0, 0);
    };

    // prologue: tile0 -> R0 -> As[0]; tile1 -> R1 (kept in regs); B0,B1 staged
    loadA(0, R0);                 // 4 vmem
    stageB(0, 0);                 // 2 vmem
    stageB(32, 1);                // 2 vmem
    loadA(32, R1);                // 4 vmem
    asm volatile("s_waitcnt vmcnt(8)" ::: "memory");   // R0 loads done
    __builtin_amdgcn_sched_barrier(0);
    writeA(R0, 0);
    asm volatile("s_waitcnt vmcnt(6) lgkmcnt(0)" ::: "memory");  // B0 glls done; R1+B1 in flight
    __builtin_amdgcn_s_barrier();
    __builtin_amdgcn_sched_barrier(0);

    // steady loop, unrolled by 2 so register sets are statically named
    for (int tt = 0; tt < ENC_NT; tt += 2) {
        // ---- even step t = tt: compute tile tt, load tile tt+2 -> R0, write tile tt+1 from R1
        {
            const int t = tt;
            const bool ld = (t + 2) < ENC_NT;
            if (ld) {
                loadA((t + 2) * 32, R0);
                stageB((t + 2) * 32, (t + 2) % 3);
            }
            mfmaStep(t & 1, t % 3);
            if (ld) asm volatile("s_waitcnt vmcnt(6)" ::: "memory");
            else    asm volatile("s_waitcnt vmcnt(0)" ::: "memory");
            __builtin_amdgcn_sched_barrier(0);
            writeA(R1, (t + 1) & 1);
            asm volatile("s_waitcnt lgkmcnt(0)" ::: "memory");
            __builtin_amdgcn_s_barrier();
            __builtin_amdgcn_sched_barrier(0);
        }
        // ---- odd step t = tt+1: compute tile t, load tile t+2 -> R1, write tile t+1 from R0
        {
            const int t = tt + 1;
            const bool ld = (t + 2) < ENC_NT;
            const bool wr1 = (t + 1) < ENC_NT;
            if (ld) {
                loadA((t + 2) * 32, R1);
                stageB((t + 2) * 32, (t + 2) % 3);
            }
            mfmaStep(t & 1, t % 3);
            if (wr1) {
                if (ld) asm volatile("s_waitcnt vmcnt(6)" ::: "memory");
                else    asm volatile("s_waitcnt vmcnt(0)" ::: "memory");
                __builtin_amdgcn_sched_barrier(0);
                writeA(R0, (t + 1) & 1);
                asm volatile("s_waitcnt lgkmcnt(0)" ::: "memory");
                __builtin_amdgcn_s_barrier();
                __builtin_amdgcn_sched_barrier(0);
            }
        }
    }

    // C/D layout: col = lane&15, row = (lane>>4)*4 + reg
#pragma unroll
    for (int ni = 0; ni < 4; ++ni) {
        int col = c0 + wc * 64 + ni * 16 + l16;
        float bv = bias[col];
#pragma unroll
        for (int mi = 0; mi < 4; ++mi) {
            int row0 = i0 + wr * 64 + mi * 16 + lh * 4;
#pragma unroll
            for (int r = 0; r < 4; ++r) {
                int row = row0 + r;
                if (row < N_NODES)
                    C[(size_t)row * HID + col] = eluf(acc[mi][ni][r] + bv);
            }
        }
    }
}

// ============ Decoder GEMM: x_recon = hd @ enc_w1 + dec_b2, M=50000 N=3000 K=512 ============
__global__ __launch_bounds__(256)
void k_dec_gemm(const __bf16* __restrict__ Ab, const __bf16* __restrict__ Bt,
                const float* __restrict__ bias, float* __restrict__ C) {
    __shared__ __bf16 As[3][4096];
    __shared__ __bf16 Bs[3][4096];
    const int tid = threadIdx.x;
    const int lane = tid & 63, wv = tid >> 6;
    const int wr = wv >> 1, wc = wv & 1;
    const int l16 = lane & 15, lh = lane >> 4;
    const int p = ((int)blockIdx.y / 24) * 8 + (int)blockIdx.x;
    if (p > 390) return;
    const int i0 = p * 128;
    const int c0 = ((int)blockIdx.y % 24) * 128;

    f32x4 acc[4][4] = {};

    auto stage = [&](int kt, int b) {
#pragma unroll
        for (int s = 0; s < 2; ++s) {
            int g = wv * 2 + s;
            int ks = g >> 1;
            int rc = (g & 1) * 64 + lane;
            int row = i0 + rc; if (row >= N_NODES) row = N_NODES - 1;
            const __bf16* srcA = Ab + (size_t)row * HID + kt + ks * 8;
            __builtin_amdgcn_global_load_lds(
                (const __attribute__((address_space(1))) void*)srcA,
                (__attribute__((address_space(3))) void*)(&As[b][(size_t)g * 512]),
                16, 0, 0);
            const __bf16* srcB = Bt + (size_t)(c0 + rc) * HID + kt + ks * 8;
            __builtin_amdgcn_global_load_lds(
                (const __attribute__((address_space(1))) void*)srcB,
                (__attribute__((address_space(3))) void*)(&Bs[b][(size_t)g * 512]),
                16, 0, 0);
        }
    };

    stage(0, 0);
    stage(32, 1);
    asm volatile("s_waitcnt vmcnt(4) lgkmcnt(0)" ::: "memory");
    __builtin_amdgcn_s_barrier();
    __builtin_amdgcn_sched_barrier(0);

#pragma unroll 1
    for (int t = 0; t < DEC_NT; ++t) {
        const int bt = t % 3;
        if (t + 2 < DEC_NT) stage((t + 2) * 32, (t + 2) % 3);
        bfv8 af[4], bfr[4];
#pragma unroll
        for (int mi = 0; mi < 4; ++mi)
            af[mi] = *(const bfv8*)&As[bt][((size_t)lh * 128 + wr * 64 + mi * 16 + l16) * 8];
#pragma unroll
        for (int ni = 0; ni < 4; ++ni)
            bfr[ni] = *(const bfv8*)&Bs[bt][((size_t)lh * 128 + wc * 64 + ni * 16 + l16) * 8];
#pragma unroll
        for (int mi = 0; mi < 4; ++mi)
#pragma unroll
            for (int ni = 0; ni < 4; ++ni)
                acc[mi][ni] = __builtin_amdgcn_mfma_f32_16x16x32_bf16(af[mi], bfr[ni], acc[mi][ni], 0, 0, 0);
        if (t + 2 < DEC_NT) {
            asm volatile("s_waitcnt vmcnt(4) lgkmcnt(0)" ::: "memory");
        } else {
            asm volatile("s_waitcnt vmcnt(0) lgkmcnt(0)" ::: "memory");
        }
        __builtin_amdgcn_s_barrier();
        __builtin_amdgcn_sched_barrier(0);
    }

#pragma unroll
    for (int ni = 0; ni < 4; ++ni) {
        int col = c0 + wc * 64 + ni * 16 + l16;
        if (col >= IN_DIM) continue;
        float bv = bias[col];
#pragma unroll
        for (int mi = 0; mi < 4; ++mi) {
            int row0 = i0 + wr * 64 + mi * 16 + lh * 4;
#pragma unroll
            for (int r = 0; r < 4; ++r) {
                int row = row0 + r;
                if (row < N_NODES)
                    C[(size_t)row * IN_DIM + col] = acc[mi][ni][r] + bv;
            }
        }
    }
}

// xh = h @ gat_w ; si/sj = att dots. 128 nodes per block.
__global__ __launch_bounds__(256)
void k_gat_proj(const float* __restrict__ h, const float* __restrict__ gat_w,
                const float* __restrict__ gat_att,
                float* __restrict__ xh, float* __restrict__ si, float* __restrict__ sj) {
    __shared__ float gwl[HID * LAT];
    __shared__ float atl[2 * LAT];
    int tid = threadIdx.x;
    for (int i = tid; i < HID * LAT; i += 256) gwl[i] = gat_w[i];
    if (tid < 2 * LAT) atl[tid] = gat_att[tid];
    __syncthreads();
    int c = tid & 31;
    bool act = c < LAT;
    for (int it = 0; it < 16; ++it) {
        int n = blockIdx.x * 128 + it * 8 + (tid >> 5);
        if (n >= N_NODES) continue;
        float accv = 0.f;
        const float4* h4 = (const float4*)(h + (size_t)n * HID);
#pragma unroll 4
        for (int j4 = 0; j4 < HID / 4; ++j4) {
            float4 hv = h4[j4];
            if (act) {
                int b = j4 * 4 * LAT + c;
                accv = fmaf(hv.x, gwl[b], accv);
                accv = fmaf(hv.y, gwl[b + LAT], accv);
                accv = fmaf(hv.z, gwl[b + 2 * LAT], accv);
                accv = fmaf(hv.w, gwl[b + 3 * LAT], accv);
            }
        }
        float xhv = act ? accv : 0.f;
        xh[(size_t)n * XH_STRIDE + c] = xhv;
        float sip = act ? atl[c] * xhv : 0.f;
        float sjp = act ? atl[LAT + c] * xhv : 0.f;
#pragma unroll
        for (int off = 16; off > 0; off >>= 1) {
            sip += __shfl_down(sip, off, 32);
            sjp += __shfl_down(sjp, off, 32);
        }
        if (c == 0) { si[n] = sip; sj[n] = sjp; }
    }
}

// ---------------- CSR build ----------------
__global__ void k_hist(const int* __restrict__ ei, unsigned* __restrict__ hist) {
    int e = blockIdx.x * 256 + threadIdx.x;
    if (e >= ET) return;
    int d = (e < E_EDGES) ? ei[E_EDGES + e] : (e - E_EDGES);
    atomicAdd(&hist[d], 1u);
}

__global__ __launch_bounds__(1024)
void k_scan(const unsigned* __restrict__ hist, unsigned* __restrict__ off, unsigned* __restrict__ cursor) {
    __shared__ unsigned part[1024];
    const int tid = threadIdx.x;
    const int b = tid * 49;
    const int e = (b + 49 < N_NODES) ? b + 49 : N_NODES;
    unsigned s = 0;
    for (int i = b; i < e; ++i) s += hist[i];
    part[tid] = s;
    __syncthreads();
    for (int d = 1; d < 1024; d <<= 1) {
        unsigned v = (tid >= d) ? part[tid - d] : 0u;
        __syncthreads();
        part[tid] += v;
        __syncthreads();
    }
    unsigned run = (tid > 0) ? part[tid - 1] : 0u;
    for (int i = b; i < e; ++i) {
        off[i] = run; cursor[i] = run;
        run += hist[i];
    }
    if (tid == 1023) off[N_NODES] = run;
}

__global__ void k_fill(const int* __restrict__ ei, const float* __restrict__ eattr,
                       unsigned* __restrict__ cursor, int* __restrict__ csr_src,
                       float* __restrict__ csr_w) {
    int e = blockIdx.x * 256 + threadIdx.x;
    if (e >= ET) return;
    int s, d; float w;
    if (e < E_EDGES) { s = ei[e]; d = ei[E_EDGES + e]; w = eattr[e]; }
    else { s = d = e - E_EDGES; w = 1.f; }
    unsigned pos = atomicAdd(&cursor[d], 1u);
    csr_src[pos] = s;
    csr_w[pos] = w;
}

// ---------------- per-dst GAT aggregation: one wave per dst ----------------
__global__ __launch_bounds__(256)
void k_gat_agg(const unsigned* __restrict__ off, const int* __restrict__ csr_src,
               const float* __restrict__ csr_w, const float* __restrict__ si,
               const float* __restrict__ sj, const float* __restrict__ xh,
               const float* __restrict__ gat_b,
               float* __restrict__ zbuf, float* __restrict__ zout) {
    const int n = blockIdx.x * 4 + (threadIdx.x >> 6);
    if (n >= N_NODES) return;
    const int lane = threadIdx.x & 63;
    const int beg = (int)off[n], end = (int)off[n + 1];
    const float s_i = si[n];
    const int c = lane & 31;
    const int half = lane >> 5;

    // pass 1: max over all edges of n
    float m = -1e30f;
    for (int j = beg + lane; j < end; j += 64) {
        int s = csr_src[j];
        float a = s_i + sj[s];
        a = a >= 0.f ? a : NEG_SLOPE * a;
        a *= csr_w[j];
        m = fmaxf(m, a);
    }
#pragma unroll
    for (int o = 32; o > 0; o >>= 1) m = fmaxf(m, __shfl_xor(m, o));

    // pass 2: exp, denom, weighted accumulation (2 edges per sub-iter via half-waves)
    float denom = 0.f, acc = 0.f;
    for (int base = beg; base < end; base += 64) {
        int j = base + lane;
        float v = 0.f; int s = 0;
        if (j < end) {
            s = csr_src[j];
            float a = s_i + sj[s];
            a = a >= 0.f ? a : NEG_SLOPE * a;
            a *= csr_w[j];
            v = __expf(a - m);
        }
        denom += v;
        int cnt = end - base; if (cnt > 64) cnt = 64;
        for (int q = 0; q < cnt; q += 2) {
            int src_lane = q + half;                  // half 0 -> edge q, half 1 -> edge q+1
            float vq = __shfl(v, src_lane);
            int sq = __shfl(s, src_lane);
            acc = fmaf(vq, xh[(size_t)sq * XH_STRIDE + c], acc);   // xh[*,30..31]==0
        }
    }
#pragma unroll
    for (int o = 32; o > 0; o >>= 1) denom += __shfl_xor(denom, o);
    acc += __shfl_xor(acc, 32);

    if (lane < LAT) {
        float v = eluf(acc / (denom + 1e-16f) + gat_b[c]);
        zbuf[(size_t)n * XH_STRIDE + c] = v;
        zout[(size_t)n * LAT + c] = v;
    }
}

// hd[i,j] = elu( sum_c z[i,c]*dec_w1[j,c] + dec_b1[j] ) -> bf16
__global__ __launch_bounds__(256)
void k_dec1(const float* __restrict__ zbuf, const float* __restrict__ wt,
            const float* __restrict__ b, __bf16* __restrict__ hdb) {
    int gid = blockIdx.x * 256 + threadIdx.x;
    if (gid >= N_NODES * HID) return;
    int j = gid & (HID - 1);
    size_t i = (size_t)(gid >> 9);
    float acc = b[j];
#pragma unroll
    for (int c = 0; c < LAT; ++c)
        acc = fmaf(zbuf[i * XH_STRIDE + c], wt[c * HID + j], acc);
    hdb[gid] = (__bf16)eluf(acc);
}

extern "C" void kernel_launch(void* const* d_in, const int* in_sizes, int n_in,
                              void* d_out, int out_size, void* d_ws, size_t ws_size,
                              hipStream_t stream) {
    const float* x      = (const float*)d_in[0];
    const int*   ei     = (const int*)d_in[1];
    const float* eattr  = (const float*)d_in[2];
    const float* enc_w1 = (const float*)d_in[3];
    const float* enc_b1 = (const float*)d_in[4];
    const float* gat_w  = (const float*)d_in[5];
    const float* gat_att= (const float*)d_in[6];
    const float* gat_b  = (const float*)d_in[7];
    const float* dec_w1 = (const float*)d_in[8];
    const float* dec_b1 = (const float*)d_in[9];
    const float* dec_b2 = (const float*)d_in[10];

    float* out  = (float*)d_out;
    float* xrec = out;
    float* zout = out + (size_t)N_NODES * IN_DIM;

    float* ws = (float*)d_ws;
    float*    h       = ws;                          // 25,600,000 f32 (h; hdb bf16 aliases later)
    float*    xh      = ws + 25600000;               //  1,600,000
    float*    zbuf    = ws + 27200000;               //  1,600,000
    float*    si      = ws + 28800000;               //     50,000
    float*    sj      = ws + 28850000;               //     50,000
    float*    wt      = ws + 28900000;               //     15,360
    __bf16*   w1b     = (__bf16*)(ws + 28915360);    //    786,432 f32-slots
    __bf16*   w1bt    = (__bf16*)(ws + 29701792);    //    786,432
    unsigned* hist    = (unsigned*)(ws + 30488224);  //     50,000
    unsigned* csr_off = (unsigned*)(ws + 30538224);  //     50,001
    unsigned* cursor  = (unsigned*)(ws + 30588226);  //     50,000
    int*      csr_src = (int*)(ws + 30638226);       //    850,000
    float*    csr_w   = (float*)(ws + 31488226);     //    850,000
    __bf16*   hdb     = (__bf16*)h;                  // 50000*512 bf16, aliases h

    (void)in_sizes; (void)n_in; (void)out_size; (void)ws_size;

    k_init<<<(N_NODES + 255) / 256, 256, 0, stream>>>(hist);
    k_transpose_w<<<(HID * LAT + 255) / 256, 256, 0, stream>>>(dec_w1, wt);
    k_conv_w<<<(HID * KPAD + 255) / 256, 256, 0, stream>>>(enc_w1, w1b, w1bt);
    k_hist<<<(ET + 255) / 256, 256, 0, stream>>>(ei, hist);

    {
        dim3 g(8, 196);   // XCD-swizzled: p=(y>>2)*8+x, c=y&3
        k_enc_gemm<<<g, 256, 0, stream>>>(x, w1b, enc_b1, h);
    }

    k_scan<<<1, 1024, 0, stream>>>(hist, csr_off, cursor);
    k_fill<<<(ET + 255) / 256, 256, 0, stream>>>(ei, eattr, cursor, csr_src, csr_w);
    k_gat_proj<<<(N_NODES + 127) / 128, 256, 0, stream>>>(h, gat_w, gat_att, xh, si, sj);
    k_gat_agg<<<(N_NODES + 3) / 4, 256, 0, stream>>>(csr_off, csr_src, csr_w, si, sj, xh, gat_b, zbuf, zout);
    k_dec1<<<(N_NODES * HID + 255) / 256, 256, 0, stream>>>(zbuf, wt, dec_b1, hdb);

    {
        dim3 g(8, 1176);  // XCD-swizzled: p=(y/24)*8+x, c=y%24
        k_dec_gemm<<<g, 256, 0, stream>>>(hdb, w1bt, dec_b2, xrec);
    }
}